// Round 8
// baseline (135.396 us; speedup 1.0000x reference)
//
#include <hip/hip_runtime.h>
#include <cmath>
#include <cstdlib>

// ===========================================================================
// HOST-SIDE table precompute.  K2 (16*9*36) and A1 (9*16) are INPUT-
// INDEPENDENT constants (exact port of _su2_cg/_q/_real_cg/_build_K, fp64).
// Built once (thread-safe magic static), memcpyAsync'd to workspace per call
// (21.3 KB; the workspace is re-poisoned between iterations so it cannot be
// cached device-side).  This removes all on-device fp64 table generation
// (phase1's 109 su2 blocks + the 21 tbl2 blocks riding on the scatter kernel).
// ===========================================================================
namespace host_tbl {

static const double F[12] = {1.0, 1.0, 2.0, 6.0, 24.0, 120.0, 720.0, 5040.0,
                             40320.0, 362880.0, 3628800.0, 39916800.0};

struct hcplx { double re, im; };
static inline hcplx cmul(hcplx a, hcplx b) {
    return { a.re * b.re - a.im * b.im, a.re * b.im + a.im * b.re };
}

static double su2_cg(int j1, int j2, int j3, int m1, int m2, int m3) {
    if (j3 < std::abs(j1 - j2) || j3 > j1 + j2) return 0.0;
    if (std::abs(m1) > j1 || std::abs(m2) > j2 || std::abs(m3) > j3) return 0.0;
    if (m3 != m1 + m2) return 0.0;
    int vmin = std::max(std::max(-j1 + j2 + m3, -j1 + m1), 0);
    int vmax = std::min(std::min(j2 + j3 + m1, j3 - j1 + j2), j3 + m3);
    if (vmax < vmin) return 0.0;
    double C = std::sqrt((2.0 * j3 + 1.0) * F[j3 + j1 - j2] * F[j3 - j1 + j2] *
                         F[j1 + j2 - j3] / F[j1 + j2 + j3 + 1] *
                         F[j3 + m3] * F[j3 - m3] /
                         (F[j1 - m1] * F[j1 + m1] * F[j2 - m2] * F[j2 + m2]));
    double S = 0.0;
    for (int v = vmin; v <= vmax; ++v) {
        double sgn = ((v + j2 + m2) & 1) ? -1.0 : 1.0;
        S += sgn / F[v] * F[j2 + j3 + m1 - v] * F[j1 - m1 + v] /
             F[j3 - j1 + j2 - v] / F[j3 + m3 - v] / F[v + j1 - j2 - m3];
    }
    return C * S;
}

static int q_col(int l, int c0, int* rows, hcplx* vals) {
    const double s = 0.7071067811865476;
    hcplx ph;
    switch (l & 3) {
        case 0: ph = {1.0, 0.0}; break;
        case 1: ph = {0.0, -1.0}; break;
        case 2: ph = {-1.0, 0.0}; break;
        default: ph = {0.0, 1.0}; break;
    }
    int mu = c0 - l;
    if (mu == 0) { rows[0] = l; vals[0] = ph; return 1; }
    if (mu > 0) {
        rows[0] = l - mu; vals[0] = cmul(ph, {s, 0.0});
        double sg = (mu & 1) ? -1.0 : 1.0;
        rows[1] = l + mu; vals[1] = cmul(ph, {sg * s, 0.0});
        return 2;
    }
    int am = -mu;
    rows[0] = l - am; vals[0] = cmul(ph, {0.0, -s});
    double sg = (am & 1) ? -1.0 : 1.0;
    rows[1] = l + am; vals[1] = cmul(ph, {0.0, sg * s});
    return 2;
}

static float real_cg(int l1, int l2, int l3, int a, int b, int c) {
    int r1[2], r2[2], r3[2];
    hcplx v1[2], v2[2], v3[2];
    int n1 = q_col(l1, a, r1, v1);
    int n2 = q_col(l2, b, r2, v2);
    int n3 = q_col(l3, c, r3, v3);
    double re = 0.0;
    for (int x = 0; x < n1; ++x)
        for (int y = 0; y < n2; ++y)
            for (int z = 0; z < n3; ++z) {
                hcplx qq = cmul(v1[x], v2[y]);
                hcplx q3c = { v3[z].re, -v3[z].im };
                qq = cmul(qq, q3c);
                double cg = su2_cg(l1, l2, l3, r1[x] - l1, r2[y] - l2, r3[z] - l3);
                re += qq.re * cg;
            }
    return (float)re;
}

static int flsqrt(int x) {
    int l = 0;
    while ((l + 1) * (l + 1) <= x) ++l;
    return l;
}

// AK layout matches workspace: [0,144) = A1, [144, 5328) = K2
static const float* get_AK() {
    static float AK[5328];
    static bool built = []() {
        for (int u = 0; u < 144; ++u) {               // A1[j*16+k]
            int j = u / 16, k = u % 16;
            int l2 = flsqrt(j), l3 = flsqrt(k);
            float v = 0.f;
            for (int i = 0; i < 4; ++i) {
                int l1 = flsqrt(i);
                if (l3 >= std::abs(l1 - l2) && l3 <= l1 + l2 && l3 <= 3)
                    v += real_cg(l1, l2, l3, i - l1 * l1, j - l2 * l2, k - l3 * l3);
            }
            AK[u] = v;
        }
        for (int t = 0; t < 16 * 9 * 36; ++t) {       // K2[t]
            int k = t % 36;
            int j = (t / 36) % 9;
            int i = t / (36 * 9);
            int l1 = flsqrt(i), l2 = flsqrt(j), l3 = flsqrt(k);
            float v = 0.f;
            if (l3 >= std::abs(l1 - l2) && l3 <= l1 + l2)
                v = real_cg(l1, l2, l3, i - l1 * l1, j - l2 * l2, k - l3 * l3);
            AK[144 + t] = v;
        }
        return true;
    }();
    (void)built;
    return AK;
}

}  // namespace host_tbl

// ===========================================================================
// Device side
// ===========================================================================
__device__ __forceinline__ void sh_from_delta(float dx, float dy, float dz, float* Y) {
    float inv = 1.f / (sqrtf(dx * dx + dy * dy + dz * dz) + 1e-12f);
    float x = dx * inv, y = dy * inv, z = dz * inv;
    const float c1 = 0.4886025119029199f;
    const float c2a = 1.0925484305920792f;
    Y[0] = 0.28209479177387814f;
    Y[1] = c1 * y; Y[2] = c1 * z; Y[3] = c1 * x;
    Y[4] = c2a * x * y;
    Y[5] = c2a * y * z;
    Y[6] = 0.31539156525252005f * (3.f * z * z - 1.f);
    Y[7] = c2a * x * z;
    Y[8] = 0.5462742152960396f * (x * x - y * y);
}

// ---------------------------------------------------------------------------
// zero_k: pure zeroing (su2 table generation moved to host)
// ---------------------------------------------------------------------------
__global__ __launch_bounds__(256) void zero_k(float* __restrict__ zero_base,
                                              long zeroN) {
    long nzb = gridDim.x;
    long zb = blockIdx.x;
    long n4 = zeroN >> 2;
    float4* p = (float4*)zero_base;
    for (long i = zb * 256 + threadIdx.x; i < n4; i += nzb * 256)
        p[i] = float4{0.f, 0.f, 0.f, 0.f};
    for (long i = (n4 << 2) + zb * 256 + threadIdx.x; i < zeroN; i += nzb * 256)
        zero_base[i] = 0.f;
}

#define OLCAP 16384
#define CH2D 2048       // edges per chunk; each chunk scanned by 8 blocks

// ---------------------------------------------------------------------------
// Phase 2d: XCD-partitioned direct scatter into ROW-MAJOR bucket with padded
// counters (count[r*16], one per 64B line).  Proven structure (r5/r7, absmax
// 0.0); at its atomic-path floor (~35-40us).  Residue partition
// (rcv>>4)&7 == blockIdx&7 keeps each 16-node row group + counter lines on
// one XCD; partition is exact so correctness never depends on dispatch.
// ---------------------------------------------------------------------------
__global__ __launch_bounds__(256) void phase2d_k(const int* __restrict__ rcv,
                                                 const int* __restrict__ snd,
                                                 const float* __restrict__ pos,
                                                 int* __restrict__ count,
                                                 int* __restrict__ bucket,
                                                 int* __restrict__ olcnt,
                                                 uint2* __restrict__ olist,
                                                 float* __restrict__ SY,
                                                 int E, int bslot) {
    int w = blockIdx.x;
    int xcd = (int)(blockIdx.x & 7);
    int chunk = w >> 3;
    int base = chunk * CH2D;
    int end = min(base + CH2D, E);
    for (int e = base + (int)threadIdx.x; e < end; e += 256) {
        int r = rcv[e];
        if (((r >> 4) & 7) != xcd) continue;
        int s = snd[e];
        int slot = atomicAdd(&count[(size_t)r << 4], 1);
        if (slot < bslot) {
            bucket[(size_t)r * bslot + slot] = s;
        } else {
            float Y[9];
            sh_from_delta(pos[3 * r] - pos[3 * s], pos[3 * r + 1] - pos[3 * s + 1],
                          pos[3 * r + 2] - pos[3 * s + 2], Y);
#pragma unroll
            for (int j = 0; j < 9; ++j) atomicAdd(&SY[r * 16 + j], Y[j]);
            int ob = atomicAdd(olcnt, 1);
            if (ob < OLCAP) olist[ob] = uint2{(unsigned)r, (unsigned)s};
        }
    }
}

// ---------------------------------------------------------------------------
// Phase 2 (OLD fallback): per-edge scatter, column-major bucket, unpadded
// count, overflow folded into SY only.
// ---------------------------------------------------------------------------
__global__ __launch_bounds__(256) void phase2_k(const int* __restrict__ rcv,
                                                const int* __restrict__ snd,
                                                const float* __restrict__ pos,
                                                int* __restrict__ count,
                                                int* __restrict__ bucket,
                                                float* __restrict__ SY,
                                                int E, int N, int slots) {
    int e = blockIdx.x * 256 + threadIdx.x;
    if (e >= E) return;
    int r = rcv[e];
    int s = snd[e];
    int slot = atomicAdd(&count[r], 1);
    if (slot < slots) {
        bucket[(size_t)slot * N + r] = s;
    } else {
        float Y[9];
        sh_from_delta(pos[3 * r] - pos[3 * s], pos[3 * r + 1] - pos[3 * s + 1],
                      pos[3 * r + 2] - pos[3 * s + 2], Y);
#pragma unroll
        for (int j = 0; j < 9; ++j) atomicAdd(&SY[r * 16 + j], Y[j]);
    }
}

__device__ __forceinline__ void node_addr(int n, int N, int npg, int bslot, int newp,
                                          long* base, int* stride) {
    if (newp) {
        *base = (long)n * bslot;
        *stride = 1;
    } else {
        *base = n;
        *stride = N;
    }
}

// ---------------------------------------------------------------------------
// Phase 3: [T2/Cc from K2/wg] || [per-node gather -> SY, 2 threads per node]
// cstride: count element stride (16 = padded new path, 1 = old path).
// ---------------------------------------------------------------------------
#define TBL3_BLOCKS 6  // ceil(1450/256)
__global__ __launch_bounds__(256) void phase3_k(const float* __restrict__ K2,
                                                const float* __restrict__ wg,
                                                const float* __restrict__ b2,
                                                const float* __restrict__ bg,
                                                int npg,
                                                float* __restrict__ T2,
                                                float* __restrict__ Cc,
                                                const float* __restrict__ pos,
                                                const int* __restrict__ count,
                                                const int* __restrict__ bucket,
                                                float* __restrict__ SY,
                                                int N, int slots, int newp, int cstride) {
    if (blockIdx.x < TBL3_BLOCKS) {
        int t = blockIdx.x * 256 + threadIdx.x;
        if (t < 1440) {
            int c = t % 10;
            int ij = t / 10;
            float acc = 0.f;
            for (int k = 0; k < 36; ++k)
                acc += K2[ij * 36 + k] * (wg[k * 10 + c] + wg[(36 + k) * 10 + c]);
            T2[t] = acc;
        } else if (t < 1450) {
            int c = t - 1440;
            float sw = 0.f;
            for (int k = 0; k < 36; ++k) sw += wg[k * 10 + c] + wg[(36 + k) * 10 + c];
            Cc[c] = (float)npg * b2[0] * sw + bg[c];
        }
    } else {
        int i = (blockIdx.x - TBL3_BLOCKS) * 256 + threadIdx.x;
        int n = i >> 1, sub = i & 1;
        if (n >= N) return;
        float rx = pos[3 * n], ry = pos[3 * n + 1], rz = pos[3 * n + 2];
        int deg = min(count[(size_t)n * cstride], slots);
        long nb; int st;
        node_addr(n, N, npg, slots, newp, &nb, &st);
        float acc[9];
#pragma unroll
        for (int j = 0; j < 9; ++j) acc[j] = 0.f;
        for (int d = sub; d < deg; d += 2) {
            int s = bucket[nb + (long)d * st];
            float Y[9];
            sh_from_delta(rx - pos[3 * s], ry - pos[3 * s + 1], rz - pos[3 * s + 2], Y);
#pragma unroll
            for (int j = 0; j < 9; ++j) acc[j] += Y[j];
        }
#pragma unroll
        for (int j = 0; j < 9; ++j) acc[j] += __shfl_xor(acc[j], 1, 64);
        if (sub == 0) {
#pragma unroll
            for (int j = 0; j < 9; ++j) SY[n * 16 + j] += acc[j];  // merge overflow atomics
        }
    }
}

__device__ __forceinline__ void accum_edge_s(const float* __restrict__ pos,
                                             const float* __restrict__ SY,
                                             int s, float rx, float ry, float rz,
                                             float* acc) {
    float Y[9];
    sh_from_delta(rx - pos[3 * s], ry - pos[3 * s + 1], rz - pos[3 * s + 2], Y);
    const float4* sp = reinterpret_cast<const float4*>(&SY[s * 16]);
    float4 s0 = sp[0], s1 = sp[1];
    float sv[9] = { s0.x, s0.y, s0.z, s0.w, s1.x, s1.y, s1.z, s1.w, SY[s * 16 + 8] };
#pragma unroll
    for (int jp = 0; jp < 9; ++jp)
#pragma unroll
        for (int j = 0; j < 9; ++j)
            acc[jp * 9 + j] += sv[jp] * Y[j];
}

// ---------------------------------------------------------------------------
// Phase 4n (NEW): one NODE per THREAD.  Prior K=5-subs structure spent ~60%
// of lane-ops on the 90-value x 6-step shuffle reduction (540 ops) vs ~350
// ops of edge work; one node/thread raises edge work 5x (deg~16 edges,
// int4-vectorized bucket-row loads) and cuts reduction instances 4x.
// bpg4 blocks per graph, nb nodes per block; overflow (deg>BSLOT) replayed
// exactly once from olist in final3.
// ---------------------------------------------------------------------------
#define TBL4_BLOCKS 4  // ceil(900/256)
__global__ __launch_bounds__(256) void phase4n_k(const float* __restrict__ A1,
                                                 const float* __restrict__ T2,
                                                 float* __restrict__ G,
                                                 float* __restrict__ H,
                                                 const float* __restrict__ pos,
                                                 const int* __restrict__ count,
                                                 const int* __restrict__ bucket,
                                                 const float* __restrict__ SY,
                                                 float* __restrict__ partial,
                                                 int npg, int bslot, int bpg4, int nb) {
    if (blockIdx.x < TBL4_BLOCKS) {
        int t = blockIdx.x * 256 + threadIdx.x;
        if (t < 810) {
            int c = t % 10;
            int jj = t / 10;
            int j = jj % 9, jp = jj / 9;
            float acc = 0.f;
            for (int i = 0; i < 16; ++i)
                acc += A1[jp * 16 + i] * T2[(i * 9 + j) * 10 + c];
            G[jj * 10 + c] = acc;
        } else if (t < 900) {
            int u = t - 810;
            int c = u % 10, j = u / 10;
            float acc = 0.f;
            for (int i = 0; i < 16; ++i) acc += T2[(i * 9 + j) * 10 + c];
            H[j * 10 + c] = acc;
        }
        return;
    }
    int bid = blockIdx.x - TBL4_BLOCKS;
    int g = bid / bpg4, q = bid - g * bpg4;
    int nl = q * nb + (int)threadIdx.x;
    float acc[90];
#pragma unroll
    for (int v = 0; v < 90; ++v) acc[v] = 0.f;
    if ((int)threadIdx.x < nb && nl < npg) {
        int n = g * npg + nl;
        float rx = pos[3 * n], ry = pos[3 * n + 1], rz = pos[3 * n + 2];
        int deg = count[(size_t)n << 4];
        if (deg > bslot) deg = bslot;  // overflow replayed via olist in final3
        const int4* row = reinterpret_cast<const int4*>(&bucket[(size_t)n * bslot]);
        for (int d0 = 0; d0 < deg; d0 += 4) {
            int4 s4 = row[d0 >> 2];
            int m = deg - d0;
            accum_edge_s(pos, SY, s4.x, rx, ry, rz, acc);
            if (m > 1) accum_edge_s(pos, SY, s4.y, rx, ry, rz, acc);
            if (m > 2) accum_edge_s(pos, SY, s4.z, rx, ry, rz, acc);
            if (m > 3) accum_edge_s(pos, SY, s4.w, rx, ry, rz, acc);
        }
#pragma unroll
        for (int j = 0; j < 9; ++j) acc[81 + j] = SY[n * 16 + j];
    }
    __shared__ float red[4][90];
#pragma unroll
    for (int v = 0; v < 90; ++v) {
        float x = acc[v];
#pragma unroll
        for (int m = 1; m < 64; m <<= 1) x += __shfl_xor(x, m, 64);
        acc[v] = x;
    }
    int lane = threadIdx.x & 63, wid = threadIdx.x >> 6;
    if (lane == 0) {
#pragma unroll
        for (int v = 0; v < 90; ++v) red[wid][v] = acc[v];
    }
    __syncthreads();
    for (int t = threadIdx.x; t < 90; t += 256) {
        float s = 0.f;
        for (int w = 0; w < 4; ++w) s += red[w][t];
        partial[(size_t)bid * 90 + t] = s;
    }
}

// ---------------------------------------------------------------------------
// Phase 4 (OLD fallback): per-node outer product, K subs/node, column bucket.
// ---------------------------------------------------------------------------
__global__ __launch_bounds__(256) void phase4_k(const float* __restrict__ A1,
                                                const float* __restrict__ T2,
                                                float* __restrict__ G,
                                                float* __restrict__ H,
                                                const float* __restrict__ pos,
                                                const int* __restrict__ snd,
                                                const int* __restrict__ rcv,
                                                const int* __restrict__ count,
                                                const int* __restrict__ bucket,
                                                const float* __restrict__ SY,
                                                float* __restrict__ partial,
                                                int N, int E, int slots, int npb, int K) {
    if (blockIdx.x < TBL4_BLOCKS) {
        int t = blockIdx.x * 256 + threadIdx.x;
        if (t < 810) {
            int c = t % 10;
            int jj = t / 10;
            int j = jj % 9, jp = jj / 9;
            float acc = 0.f;
            for (int i = 0; i < 16; ++i)
                acc += A1[jp * 16 + i] * T2[(i * 9 + j) * 10 + c];
            G[jj * 10 + c] = acc;
        } else if (t < 900) {
            int u = t - 810;
            int c = u % 10, j = u / 10;
            float acc = 0.f;
            for (int i = 0; i < 16; ++i) acc += T2[(i * 9 + j) * 10 + c];
            H[j * 10 + c] = acc;
        }
        return;
    }
    int bid = blockIdx.x - TBL4_BLOCKS;
    int node_local = (int)threadIdx.x % npb;
    int sub = (int)threadIdx.x / npb;
    int n = bid * npb + node_local;
    float acc[90];
#pragma unroll
    for (int v = 0; v < 90; ++v) acc[v] = 0.f;
    if (sub < K && n < N) {
        float rx = pos[3 * n], ry = pos[3 * n + 1], rz = pos[3 * n + 2];
        int deg = count[n];
        if (deg <= slots) {
            for (int d = sub; d < deg; d += K)
                accum_edge_s(pos, SY, bucket[(size_t)d * N + n], rx, ry, rz, acc);
        } else {
            for (int e = sub; e < E; e += K)
                if (rcv[e] == n) accum_edge_s(pos, SY, snd[e], rx, ry, rz, acc);
        }
        if (sub == 0) {
#pragma unroll
            for (int j = 0; j < 9; ++j) acc[81 + j] = SY[n * 16 + j];
        }
    }
    __shared__ float red[4][90];
#pragma unroll
    for (int v = 0; v < 90; ++v) {
        float x = acc[v];
#pragma unroll
        for (int m = 1; m < 64; m <<= 1) x += __shfl_xor(x, m, 64);
        acc[v] = x;
    }
    int lane = threadIdx.x & 63, wid = threadIdx.x >> 6;
    if (lane == 0) {
#pragma unroll
        for (int v = 0; v < 90; ++v) red[wid][v] = acc[v];
    }
    __syncthreads();
    int nw = blockDim.x >> 6;
    for (int t = threadIdx.x; t < 90; t += blockDim.x) {
        float s = 0.f;
        for (int w = 0; w < nw; ++w) s += red[w][t];
        partial[bid * 90 + t] = s;
    }
}

// ---------------------------------------------------------------------------
// Phase 5: one block per graph.  Partial-reduce + overflow-list replay +
// final affine.
// ---------------------------------------------------------------------------
__global__ __launch_bounds__(128) void final3_k(const float* __restrict__ G,
                                                const float* __restrict__ H,
                                                const float* __restrict__ partial,
                                                const float* __restrict__ Cc,
                                                const float* __restrict__ w1,
                                                const float* __restrict__ b1,
                                                const float* __restrict__ w2,
                                                const float* __restrict__ pos,
                                                const float* __restrict__ SY,
                                                const int* __restrict__ olcnt,
                                                const uint2* __restrict__ olist,
                                                float* __restrict__ out,
                                                int bpg, int npg) {
    __shared__ float Ms[90];
    __shared__ float Gs[810];
    __shared__ float Hs[90];
    int g = blockIdx.x;
    int tid = threadIdx.x;
    for (int t = tid; t < 810; t += 128) Gs[t] = G[t];
    for (int t = tid; t < 90; t += 128) Hs[t] = H[t];
    const float* pg = &partial[(size_t)g * bpg * 90];
    for (int v = tid; v < 90; v += 128) {
        float m = 0.f;
        for (int q = 0; q < bpg; ++q) m += pg[q * 90 + v];
        Ms[v] = m;
    }
    __syncthreads();
    int oc = min(olcnt[0], OLCAP);
    for (int i = tid; i < oc; i += 128) {
        uint2 es = olist[i];
        int r = (int)es.x;
        if (r / npg != g) continue;
        int s = (int)es.y;
        float Y[9];
        sh_from_delta(pos[3 * r] - pos[3 * s], pos[3 * r + 1] - pos[3 * s + 1],
                      pos[3 * r + 2] - pos[3 * s + 2], Y);
#pragma unroll
        for (int jp = 0; jp < 9; ++jp) {
            float sv = SY[s * 16 + jp];
#pragma unroll
            for (int j = 0; j < 9; ++j) atomicAdd(&Ms[jp * 9 + j], sv * Y[j]);
        }
    }
    __syncthreads();
    if (tid < 10) {
        int c = tid;
        float z = 0.f;
#pragma unroll
        for (int idx = 0; idx < 81; ++idx) z += Gs[idx * 10 + c] * Ms[idx];
        float z2 = 0.f;
#pragma unroll
        for (int j = 0; j < 9; ++j) z2 += Hs[j * 10 + c] * Ms[81 + j];
        out[g * 10 + c] = w2[0] * (w1[0] * z + b1[0] * z2) + Cc[c];
    }
}

extern "C" void kernel_launch(void* const* d_in, const int* in_sizes, int n_in,
                              void* d_out, int out_size, void* d_ws, size_t ws_size,
                              hipStream_t stream) {
    const float* pos = (const float*)d_in[0];
    const float* w1  = (const float*)d_in[1];
    const float* b1  = (const float*)d_in[2];
    const float* w2  = (const float*)d_in[3];
    const float* b2  = (const float*)d_in[4];
    const float* wg  = (const float*)d_in[5];
    const float* bg  = (const float*)d_in[6];
    const int* snd   = (const int*)d_in[7];
    const int* rcv   = (const int*)d_in[8];

    int N = in_sizes[0] / 3;
    int E = in_sizes[7];
    int nG = out_size / 10;          // n_graphs
    int npg = N / nG;                // nodes per graph (800)

    float* ws = (float*)d_ws;
    float* A1  = ws + 0;       // 144   (host-precomputed)
    float* K2  = ws + 144;     // 5184  (host-precomputed)
    float* T2  = ws + 5328;    // 1440
    float* Cc  = ws + 6768;    // 16
    float* Gt  = ws + 6784;    // 816
    float* Ht  = ws + 7600;    // 96
    size_t c0 = 63136;         // keep legacy offset (su2tab region now unused)
    size_t wsFloats = ws_size / 4;

    // Host-constant tables -> workspace (21.3 KB, overlaps nothing)
    hipMemcpyAsync(ws, host_tbl::get_AK(), 5328 * sizeof(float),
                   hipMemcpyHostToDevice, stream);

    // ---- NEW layout (round-7 champion) ----
    // [count(16N, padded 1/line) | SY(16N) | olcnt(16) | bucket(BSLOT*N) |
    //  olist(2*OLCAP) | partial(nG*bpg4*90)]
    const int BSLOT = 40;
    int bpg4 = (npg + 255) / 256;                 // blocks per graph (800 -> 4)
    int nb   = (npg + bpg4 - 1) / bpg4;           // nodes per block (200)
    int NB4  = nG * bpg4;
    size_t sy_off    = c0 + 16 * (size_t)N;
    size_t olcnt_off = sy_off + 16 * (size_t)N;
    size_t zeroN     = 32 * (size_t)N + 16;
    size_t b0        = c0 + zeroN;
    size_t olist_off = b0 + (size_t)BSLOT * N;
    size_t part_off  = olist_off + 2 * (size_t)OLCAP;
    size_t new_end   = part_off + (size_t)NB4 * 90;
    bool newp = (npg * nG == N) && (nG > 0) && (nb <= 256) && (new_end <= wsFloats);

    if (newp) {
        int* count   = (int*)ws + c0;
        float* SY    = ws + sy_off;
        int* olcnt   = (int*)ws + olcnt_off;
        int* bucket  = (int*)ws + b0;
        uint2* olist = (uint2*)(ws + olist_off);
        float* part  = ws + part_off;
        zero_k<<<128, 256, 0, stream>>>(ws + c0, (long)zeroN);
        int nCH = (E + CH2D - 1) / CH2D;
        phase2d_k<<<nCH * 8, 256, 0, stream>>>(
            rcv, snd, pos, count, bucket, olcnt, olist, SY, E, BSLOT);
        phase3_k<<<TBL3_BLOCKS + (2 * N + 255) / 256, 256, 0, stream>>>(
            K2, wg, b2, bg, npg, T2, Cc, pos, count, bucket, SY, N, BSLOT, 1, 16);
        phase4n_k<<<TBL4_BLOCKS + NB4, 256, 0, stream>>>(
            A1, T2, Gt, Ht, pos, count, bucket, SY, part, npg, BSLOT, bpg4, nb);
        final3_k<<<nG, 128, 0, stream>>>(Gt, Ht, part, Cc, w1, b1, w2, pos, SY,
                                         olcnt, olist, (float*)d_out, bpg4, npg);
    } else {
        // ---- OLD fallback: unpadded count | SY | olcnt | part | bucket ----
        int npb = 1;
        for (int d = 1; d <= 64 && d <= npg; ++d) if (npg % d == 0) npb = d;
        int K = 256 / npb; if (K > 8) K = 8;
        int bpg = (npb > 0) ? npg / npb : 1;
        int NB2 = nG * bpg;
        int* count = (int*)ws + c0;
        float* SY  = ws + c0 + N;
        int* olcnt = (int*)ws + c0 + 17 * (size_t)N;
        size_t zN  = 17 * (size_t)N + 16;
        size_t ob0 = c0 + zN;
        float* part = ws + ob0;
        size_t buck_off = ob0 + (size_t)NB2 * 90;
        int* bucket = (int*)ws + buck_off;
        long avail = (long)wsFloats - (long)buck_off;
        int slots = 0;
        if (avail > 0) slots = (int)(avail / (long)N);
        if (slots > 48) slots = 48;
        zero_k<<<128, 256, 0, stream>>>(ws + c0, (long)zN);
        phase2_k<<<(E + 255) / 256, 256, 0, stream>>>(
            rcv, snd, pos, count, bucket, SY, E, N, slots);
        phase3_k<<<TBL3_BLOCKS + (2 * N + 255) / 256, 256, 0, stream>>>(
            K2, wg, b2, bg, npg, T2, Cc, pos, count, bucket, SY, N, slots, 0, 1);
        phase4_k<<<TBL4_BLOCKS + NB2, 256, 0, stream>>>(
            A1, T2, Gt, Ht, pos, snd, rcv, count, bucket, SY, part, N, E, slots, npb, K);
        final3_k<<<nG, 128, 0, stream>>>(Gt, Ht, part, Cc, w1, b1, w2, pos, SY,
                                         olcnt, (uint2*)(ws + olist_off), (float*)d_out,
                                         bpg, npg);
    }
}

// Round 9
// 93.065 us; speedup vs baseline: 1.4548x; 1.4548x over previous
//
#include <hip/hip_runtime.h>

// ---------------------------------------------------------------------------
// On-device Clebsch-Gordan tables (exact port of _su2_cg/_q/_real_cg/_build_K,
// fp64).  Factorials from constant LUT; su2_cg precomputed into a dense table.
// NOTE (r8 post-mortem): host-precompute + hipMemcpyAsync from pageable
// memory REGRESSED 105->135us (pageable H2D staging replays per graph
// iteration).  On-device generation rides concurrently with zeroing /
// the scatter grid and is effectively free -- keep it on device.
// ---------------------------------------------------------------------------
__device__ __constant__ double FACT[12] = {
    1.0, 1.0, 2.0, 6.0, 24.0, 120.0, 720.0, 5040.0,
    40320.0, 362880.0, 3628800.0, 39916800.0
};

struct cplx { double re, im; };
__device__ __forceinline__ cplx cmul(cplx a, cplx b) {
    return { a.re * b.re - a.im * b.im, a.re * b.im + a.im * b.re };
}

__device__ double su2_cg_full(int j1, int j2, int j3, int m1, int m2, int m3) {
    if (j3 < abs(j1 - j2) || j3 > j1 + j2) return 0.0;
    if (abs(m1) > j1 || abs(m2) > j2 || abs(m3) > j3) return 0.0;
    if (m3 != m1 + m2) return 0.0;
    int vmin = max(max(-j1 + j2 + m3, -j1 + m1), 0);
    int vmax = min(min(j2 + j3 + m1, j3 - j1 + j2), j3 + m3);
    if (vmax < vmin) return 0.0;
    double C = sqrt((2.0 * j3 + 1.0) * FACT[j3 + j1 - j2] * FACT[j3 - j1 + j2] *
                    FACT[j1 + j2 - j3] / FACT[j1 + j2 + j3 + 1] *
                    FACT[j3 + m3] * FACT[j3 - m3] /
                    (FACT[j1 - m1] * FACT[j1 + m1] * FACT[j2 - m2] * FACT[j2 + m2]));
    double S = 0.0;
    for (int v = vmin; v <= vmax; ++v) {
        double sgn = ((v + j2 + m2) & 1) ? -1.0 : 1.0;
        S += sgn / FACT[v] * FACT[j2 + j3 + m1 - v] * FACT[j1 - m1 + v] /
             FACT[j3 - j1 + j2 - v] / FACT[j3 + m3 - v] / FACT[v + j1 - j2 - m3];
    }
    return C * S;
}

__device__ __forceinline__ int su2_idx(int l1, int l2, int l3, int m1, int m2, int m3) {
    return ((((l1 * 3 + l2) * 6 + l3) * 7 + (m1 + 3)) * 5 + (m2 + 2)) * 11 + (m3 + 5);
}
#define SU2_TAB_SIZE 27720  // 4*3*6*7*5*11

__device__ int q_col(int l, int c0, int* rows, cplx* vals) {
    const double s = 0.7071067811865476;
    cplx ph;  // (-i)^l
    switch (l & 3) {
        case 0: ph = {1.0, 0.0}; break;
        case 1: ph = {0.0, -1.0}; break;
        case 2: ph = {-1.0, 0.0}; break;
        default: ph = {0.0, 1.0}; break;
    }
    int mu = c0 - l;
    if (mu == 0) { rows[0] = l; vals[0] = ph; return 1; }
    if (mu > 0) {
        rows[0] = l - mu; vals[0] = cmul(ph, {s, 0.0});
        double sg = (mu & 1) ? -1.0 : 1.0;
        rows[1] = l + mu; vals[1] = cmul(ph, {sg * s, 0.0});
        return 2;
    }
    int am = -mu;
    rows[0] = l - am; vals[0] = cmul(ph, {0.0, -s});
    double sg = (am & 1) ? -1.0 : 1.0;
    rows[1] = l + am; vals[1] = cmul(ph, {0.0, sg * s});
    return 2;
}

__device__ float real_cg_elem_tab(const double* __restrict__ su2tab,
                                  int l1, int l2, int l3, int a, int b, int c) {
    int r1[2], r2[2], r3[2];
    cplx v1[2], v2[2], v3[2];
    int n1 = q_col(l1, a, r1, v1);
    int n2 = q_col(l2, b, r2, v2);
    int n3 = q_col(l3, c, r3, v3);
    double re = 0.0;
    for (int x = 0; x < n1; ++x)
        for (int y = 0; y < n2; ++y)
            for (int z = 0; z < n3; ++z) {
                cplx qq = cmul(v1[x], v2[y]);
                cplx q3c = { v3[z].re, -v3[z].im };
                qq = cmul(qq, q3c);
                double cg = su2tab[su2_idx(l1, l2, l3, r1[x] - l1, r2[y] - l2, r3[z] - l3)];
                re += qq.re * cg;
            }
    return (float)re;
}

__device__ int flsqrt(int x) {
    int l = 0;
    while ((l + 1) * (l + 1) <= x) ++l;
    return l;
}

__device__ __forceinline__ void sh_from_delta(float dx, float dy, float dz, float* Y) {
    float inv = 1.f / (sqrtf(dx * dx + dy * dy + dz * dz) + 1e-12f);
    float x = dx * inv, y = dy * inv, z = dz * inv;
    const float c1 = 0.4886025119029199f;
    const float c2a = 1.0925484305920792f;
    Y[0] = 0.28209479177387814f;
    Y[1] = c1 * y; Y[2] = c1 * z; Y[3] = c1 * x;
    Y[4] = c2a * x * y;
    Y[5] = c2a * y * z;
    Y[6] = 0.31539156525252005f * (3.f * z * z - 1.f);
    Y[7] = c2a * x * z;
    Y[8] = 0.5462742152960396f * (x * x - y * y);
}

// table-assembly helper shared by phase2d_k (new) and phase2_k (old)
__device__ void tbl2_work(const double* __restrict__ su2tab, int t,
                          float* __restrict__ A1, float* __restrict__ K2) {
    const int NK2 = 16 * 9 * 36;
    if (t < NK2) {
        int k = t % 36;
        int j = (t / 36) % 9;
        int i = t / (36 * 9);
        int l1 = flsqrt(i), l2 = flsqrt(j), l3 = flsqrt(k);
        float v = 0.f;
        if (l3 >= abs(l1 - l2) && l3 <= l1 + l2)
            v = real_cg_elem_tab(su2tab, l1, l2, l3, i - l1 * l1, j - l2 * l2, k - l3 * l3);
        K2[t] = v;
    } else if (t < NK2 + 144) {
        int u = t - NK2;
        int j = u / 16, k = u % 16;
        int l2 = flsqrt(j), l3 = flsqrt(k);
        float v = 0.f;
        for (int i = 0; i < 4; ++i) {
            int l1 = flsqrt(i);
            if (l3 >= abs(l1 - l2) && l3 <= l1 + l2 && l3 <= 3)
                v += real_cg_elem_tab(su2tab, l1, l2, l3, i - l1 * l1, j - l2 * l2, k - l3 * l3);
        }
        A1[u] = v;
    }
}

// ---------------------------------------------------------------------------
// Phase 1: [su2 table] || [zero count+SY+olcnt]
// ---------------------------------------------------------------------------
#define SU2_BLOCKS 109  // ceil(27720/256)
__global__ __launch_bounds__(256) void phase1_k(double* __restrict__ su2tab,
                                                float* __restrict__ zero_base,
                                                long zeroN) {
    if (blockIdx.x < SU2_BLOCKS) {
        int t = blockIdx.x * 256 + threadIdx.x;
        if (t < SU2_TAB_SIZE) {
            int r = t;
            int im3 = r % 11; r /= 11;
            int im2 = r % 5;  r /= 5;
            int im1 = r % 7;  r /= 7;
            int l3  = r % 6;  r /= 6;
            int l2  = r % 3;  r /= 3;
            int l1  = r;
            su2tab[t] = su2_cg_full(l1, l2, l3, im1 - 3, im2 - 2, im3 - 5);
        }
    } else {
        long zb = blockIdx.x - SU2_BLOCKS;
        long nzb = gridDim.x - SU2_BLOCKS;
        long n4 = zeroN >> 2;
        float4* p = (float4*)zero_base;
        for (long i = zb * 256 + threadIdx.x; i < n4; i += nzb * 256)
            p[i] = float4{0.f, 0.f, 0.f, 0.f};
        for (long i = (n4 << 2) + zb * 256 + threadIdx.x; i < zeroN; i += nzb * 256)
            zero_base[i] = 0.f;
    }
}

#define TBL2_BLOCKS 21  // ceil(5328/256)
#define OLCAP 16384
#define CH2D 2048       // edges per chunk; each chunk scanned by 8 blocks

// ---------------------------------------------------------------------------
// Phase 2d: XCD-partitioned direct scatter into ROW-MAJOR bucket, with
// PADDED degree counters: count[r*16] -- one counter per 64B cache line.
// Proven structure (r5/r7, absmax 0.0); at its atomic-path floor (~35-40us).
// The (rcv>>4)&7 == blockIdx&7 residue partition keeps each 16-node row
// group + its counter lines on ONE XCD; partition is exact, so correctness
// never depends on the dispatch heuristic.
// count[r*16] holds raw degree; overflow -> SY atomics + olist (BSLOT=40 =>
// expected overflow 0 at Poisson(16) in-degree).
// ---------------------------------------------------------------------------
__global__ __launch_bounds__(256) void phase2d_k(const double* __restrict__ su2tab,
                                                 float* __restrict__ A1,
                                                 float* __restrict__ K2,
                                                 const int* __restrict__ rcv,
                                                 const int* __restrict__ snd,
                                                 const float* __restrict__ pos,
                                                 int* __restrict__ count,
                                                 int* __restrict__ bucket,
                                                 int* __restrict__ olcnt,
                                                 uint2* __restrict__ olist,
                                                 float* __restrict__ SY,
                                                 int E, int bslot) {
    if (blockIdx.x < TBL2_BLOCKS) {
        tbl2_work(su2tab, blockIdx.x * 256 + threadIdx.x, A1, K2);
        return;
    }
    int w = blockIdx.x - TBL2_BLOCKS;
    int xcd = (int)(blockIdx.x & 7);   // match empirical round-robin dispatch
    int chunk = w >> 3;
    int base = chunk * CH2D;
    int end = min(base + CH2D, E);
    for (int e = base + (int)threadIdx.x; e < end; e += 256) {
        int r = rcv[e];
        if (((r >> 4) & 7) != xcd) continue;
        int s = snd[e];
        int slot = atomicAdd(&count[(size_t)r << 4], 1);
        if (slot < bslot) {
            bucket[(size_t)r * bslot + slot] = s;
        } else {
            float Y[9];
            sh_from_delta(pos[3 * r] - pos[3 * s], pos[3 * r + 1] - pos[3 * s + 1],
                          pos[3 * r + 2] - pos[3 * s + 2], Y);
#pragma unroll
            for (int j = 0; j < 9; ++j) atomicAdd(&SY[r * 16 + j], Y[j]);
            int ob = atomicAdd(olcnt, 1);
            if (ob < OLCAP) olist[ob] = uint2{(unsigned)r, (unsigned)s};
        }
    }
}

// ---------------------------------------------------------------------------
// Phase 2 (OLD fallback): [K2/A1] || [per-edge scatter, column-major bucket,
// unpadded count, overflow folded into SY only]
// ---------------------------------------------------------------------------
__global__ __launch_bounds__(256) void phase2_k(const double* __restrict__ su2tab,
                                                float* __restrict__ A1,
                                                float* __restrict__ K2,
                                                const int* __restrict__ rcv,
                                                const int* __restrict__ snd,
                                                const float* __restrict__ pos,
                                                int* __restrict__ count,
                                                int* __restrict__ bucket,
                                                float* __restrict__ SY,
                                                int E, int N, int slots) {
    if (blockIdx.x < TBL2_BLOCKS) {
        tbl2_work(su2tab, blockIdx.x * 256 + threadIdx.x, A1, K2);
        return;
    }
    int e = (blockIdx.x - TBL2_BLOCKS) * 256 + threadIdx.x;
    if (e >= E) return;
    int r = rcv[e];
    int s = snd[e];
    int slot = atomicAdd(&count[r], 1);
    if (slot < slots) {
        bucket[(size_t)slot * N + r] = s;
    } else {
        float Y[9];
        sh_from_delta(pos[3 * r] - pos[3 * s], pos[3 * r + 1] - pos[3 * s + 1],
                      pos[3 * r + 2] - pos[3 * s + 2], Y);
#pragma unroll
        for (int j = 0; j < 9; ++j) atomicAdd(&SY[r * 16 + j], Y[j]);
    }
}

// node -> (bucket base, stride) for unified old/new indexing
__device__ __forceinline__ void node_addr(int n, int N, int npg, int bslot, int newp,
                                          long* base, int* stride) {
    if (newp) {
        *base = (long)n * bslot;
        *stride = 1;
    } else {
        *base = n;
        *stride = N;
    }
}

// ---------------------------------------------------------------------------
// Phase 3: [T2/Cc] || [per-node gather -> SY, 2 threads per node]
// cstride: count element stride (16 = padded new path, 1 = old path).
// ---------------------------------------------------------------------------
#define TBL3_BLOCKS 6  // ceil(1450/256)
__global__ __launch_bounds__(256) void phase3_k(const float* __restrict__ K2,
                                                const float* __restrict__ wg,
                                                const float* __restrict__ b2,
                                                const float* __restrict__ bg,
                                                int npg,
                                                float* __restrict__ T2,
                                                float* __restrict__ Cc,
                                                const float* __restrict__ pos,
                                                const int* __restrict__ count,
                                                const int* __restrict__ bucket,
                                                float* __restrict__ SY,
                                                int N, int slots, int newp, int cstride) {
    if (blockIdx.x < TBL3_BLOCKS) {
        int t = blockIdx.x * 256 + threadIdx.x;
        if (t < 1440) {
            int c = t % 10;
            int ij = t / 10;
            float acc = 0.f;
            for (int k = 0; k < 36; ++k)
                acc += K2[ij * 36 + k] * (wg[k * 10 + c] + wg[(36 + k) * 10 + c]);
            T2[t] = acc;
        } else if (t < 1450) {
            int c = t - 1440;
            float sw = 0.f;
            for (int k = 0; k < 36; ++k) sw += wg[k * 10 + c] + wg[(36 + k) * 10 + c];
            Cc[c] = (float)npg * b2[0] * sw + bg[c];
        }
    } else {
        int i = (blockIdx.x - TBL3_BLOCKS) * 256 + threadIdx.x;
        int n = i >> 1, sub = i & 1;
        if (n >= N) return;
        float rx = pos[3 * n], ry = pos[3 * n + 1], rz = pos[3 * n + 2];
        int deg = min(count[(size_t)n * cstride], slots);
        long nb; int st;
        node_addr(n, N, npg, slots, newp, &nb, &st);
        float acc[9];
#pragma unroll
        for (int j = 0; j < 9; ++j) acc[j] = 0.f;
        for (int d = sub; d < deg; d += 2) {
            int s = bucket[nb + (long)d * st];
            float Y[9];
            sh_from_delta(rx - pos[3 * s], ry - pos[3 * s + 1], rz - pos[3 * s + 2], Y);
#pragma unroll
            for (int j = 0; j < 9; ++j) acc[j] += Y[j];
        }
#pragma unroll
        for (int j = 0; j < 9; ++j) acc[j] += __shfl_xor(acc[j], 1, 64);
        if (sub == 0) {
#pragma unroll
            for (int j = 0; j < 9; ++j) SY[n * 16 + j] += acc[j];  // merge overflow atomics
        }
    }
}

__device__ __forceinline__ void accum_edge_s(const float* __restrict__ pos,
                                             const float* __restrict__ SY,
                                             int s, float rx, float ry, float rz,
                                             float* acc) {
    float Y[9];
    sh_from_delta(rx - pos[3 * s], ry - pos[3 * s + 1], rz - pos[3 * s + 2], Y);
    const float4* sp = reinterpret_cast<const float4*>(&SY[s * 16]);
    float4 s0 = sp[0], s1 = sp[1];
    float sv[9] = { s0.x, s0.y, s0.z, s0.w, s1.x, s1.y, s1.z, s1.w, SY[s * 16 + 8] };
#pragma unroll
    for (int jp = 0; jp < 9; ++jp)
#pragma unroll
        for (int j = 0; j < 9; ++j)
            acc[jp * 9 + j] += sv[jp] * Y[j];
}

// ---------------------------------------------------------------------------
// Phase 4n (A/B vs r7's phase4_k): one NODE per THREAD.  Same total edge
// work; 4x fewer 90-value block reductions (260 vs 1028 blocks); deg~16
// edges/thread with int4-vectorized bucket-row loads.  Overflow (deg>BSLOT)
// replayed exactly once from olist in final3.
// ---------------------------------------------------------------------------
#define TBL4_BLOCKS 4  // ceil(900/256)
__global__ __launch_bounds__(256) void phase4n_k(const float* __restrict__ A1,
                                                 const float* __restrict__ T2,
                                                 float* __restrict__ G,
                                                 float* __restrict__ H,
                                                 const float* __restrict__ pos,
                                                 const int* __restrict__ count,
                                                 const int* __restrict__ bucket,
                                                 const float* __restrict__ SY,
                                                 float* __restrict__ partial,
                                                 int npg, int bslot, int bpg4, int nb) {
    if (blockIdx.x < TBL4_BLOCKS) {
        int t = blockIdx.x * 256 + threadIdx.x;
        if (t < 810) {
            int c = t % 10;
            int jj = t / 10;
            int j = jj % 9, jp = jj / 9;
            float acc = 0.f;
            for (int i = 0; i < 16; ++i)
                acc += A1[jp * 16 + i] * T2[(i * 9 + j) * 10 + c];
            G[jj * 10 + c] = acc;
        } else if (t < 900) {
            int u = t - 810;
            int c = u % 10, j = u / 10;
            float acc = 0.f;
            for (int i = 0; i < 16; ++i) acc += T2[(i * 9 + j) * 10 + c];
            H[j * 10 + c] = acc;
        }
        return;
    }
    int bid = blockIdx.x - TBL4_BLOCKS;
    int g = bid / bpg4, q = bid - g * bpg4;
    int nl = q * nb + (int)threadIdx.x;
    float acc[90];
#pragma unroll
    for (int v = 0; v < 90; ++v) acc[v] = 0.f;
    if ((int)threadIdx.x < nb && nl < npg) {
        int n = g * npg + nl;
        float rx = pos[3 * n], ry = pos[3 * n + 1], rz = pos[3 * n + 2];
        int deg = count[(size_t)n << 4];
        if (deg > bslot) deg = bslot;  // overflow replayed via olist in final3
        const int4* row = reinterpret_cast<const int4*>(&bucket[(size_t)n * bslot]);
        for (int d0 = 0; d0 < deg; d0 += 4) {
            int4 s4 = row[d0 >> 2];
            int m = deg - d0;
            accum_edge_s(pos, SY, s4.x, rx, ry, rz, acc);
            if (m > 1) accum_edge_s(pos, SY, s4.y, rx, ry, rz, acc);
            if (m > 2) accum_edge_s(pos, SY, s4.z, rx, ry, rz, acc);
            if (m > 3) accum_edge_s(pos, SY, s4.w, rx, ry, rz, acc);
        }
#pragma unroll
        for (int j = 0; j < 9; ++j) acc[81 + j] = SY[n * 16 + j];
    }
    __shared__ float red[4][90];
#pragma unroll
    for (int v = 0; v < 90; ++v) {
        float x = acc[v];
#pragma unroll
        for (int m = 1; m < 64; m <<= 1) x += __shfl_xor(x, m, 64);
        acc[v] = x;
    }
    int lane = threadIdx.x & 63, wid = threadIdx.x >> 6;
    if (lane == 0) {
#pragma unroll
        for (int v = 0; v < 90; ++v) red[wid][v] = acc[v];
    }
    __syncthreads();
    for (int t = threadIdx.x; t < 90; t += 256) {
        float s = 0.f;
        for (int w = 0; w < 4; ++w) s += red[w][t];
        partial[(size_t)bid * 90 + t] = s;
    }
}

// ---------------------------------------------------------------------------
// Phase 4 (OLD fallback): per-node outer product, K subs/node, column bucket.
// ---------------------------------------------------------------------------
__global__ __launch_bounds__(256) void phase4_k(const float* __restrict__ A1,
                                                const float* __restrict__ T2,
                                                float* __restrict__ G,
                                                float* __restrict__ H,
                                                const float* __restrict__ pos,
                                                const int* __restrict__ snd,
                                                const int* __restrict__ rcv,
                                                const int* __restrict__ count,
                                                const int* __restrict__ bucket,
                                                const float* __restrict__ SY,
                                                float* __restrict__ partial,
                                                int N, int E, int slots, int npb, int K) {
    if (blockIdx.x < TBL4_BLOCKS) {
        int t = blockIdx.x * 256 + threadIdx.x;
        if (t < 810) {
            int c = t % 10;
            int jj = t / 10;
            int j = jj % 9, jp = jj / 9;
            float acc = 0.f;
            for (int i = 0; i < 16; ++i)
                acc += A1[jp * 16 + i] * T2[(i * 9 + j) * 10 + c];
            G[jj * 10 + c] = acc;
        } else if (t < 900) {
            int u = t - 810;
            int c = u % 10, j = u / 10;
            float acc = 0.f;
            for (int i = 0; i < 16; ++i) acc += T2[(i * 9 + j) * 10 + c];
            H[j * 10 + c] = acc;
        }
        return;
    }
    int bid = blockIdx.x - TBL4_BLOCKS;
    int node_local = (int)threadIdx.x % npb;
    int sub = (int)threadIdx.x / npb;
    int n = bid * npb + node_local;
    float acc[90];
#pragma unroll
    for (int v = 0; v < 90; ++v) acc[v] = 0.f;
    if (sub < K && n < N) {
        float rx = pos[3 * n], ry = pos[3 * n + 1], rz = pos[3 * n + 2];
        int deg = count[n];
        if (deg <= slots) {
            for (int d = sub; d < deg; d += K)
                accum_edge_s(pos, SY, bucket[(size_t)d * N + n], rx, ry, rz, acc);
        } else {
            for (int e = sub; e < E; e += K)
                if (rcv[e] == n) accum_edge_s(pos, SY, snd[e], rx, ry, rz, acc);
        }
        if (sub == 0) {
#pragma unroll
            for (int j = 0; j < 9; ++j) acc[81 + j] = SY[n * 16 + j];
        }
    }
    __shared__ float red[4][90];
#pragma unroll
    for (int v = 0; v < 90; ++v) {
        float x = acc[v];
#pragma unroll
        for (int m = 1; m < 64; m <<= 1) x += __shfl_xor(x, m, 64);
        acc[v] = x;
    }
    int lane = threadIdx.x & 63, wid = threadIdx.x >> 6;
    if (lane == 0) {
#pragma unroll
        for (int v = 0; v < 90; ++v) red[wid][v] = acc[v];
    }
    __syncthreads();
    int nw = blockDim.x >> 6;
    for (int t = threadIdx.x; t < 90; t += blockDim.x) {
        float s = 0.f;
        for (int w = 0; w < nw; ++w) s += red[w][t];
        partial[bid * 90 + t] = s;
    }
}

// ---------------------------------------------------------------------------
// Phase 5: one block per graph.  Partial-reduce + overflow-list replay +
// final affine.
// ---------------------------------------------------------------------------
__global__ __launch_bounds__(128) void final3_k(const float* __restrict__ G,
                                                const float* __restrict__ H,
                                                const float* __restrict__ partial,
                                                const float* __restrict__ Cc,
                                                const float* __restrict__ w1,
                                                const float* __restrict__ b1,
                                                const float* __restrict__ w2,
                                                const float* __restrict__ pos,
                                                const float* __restrict__ SY,
                                                const int* __restrict__ olcnt,
                                                const uint2* __restrict__ olist,
                                                float* __restrict__ out,
                                                int bpg, int npg) {
    __shared__ float Ms[90];
    __shared__ float Gs[810];
    __shared__ float Hs[90];
    int g = blockIdx.x;
    int tid = threadIdx.x;
    for (int t = tid; t < 810; t += 128) Gs[t] = G[t];
    for (int t = tid; t < 90; t += 128) Hs[t] = H[t];
    const float* pg = &partial[(size_t)g * bpg * 90];
    for (int v = tid; v < 90; v += 128) {
        float m = 0.f;
        for (int q = 0; q < bpg; ++q) m += pg[q * 90 + v];
        Ms[v] = m;
    }
    __syncthreads();
    int oc = min(olcnt[0], OLCAP);
    for (int i = tid; i < oc; i += 128) {
        uint2 es = olist[i];
        int r = (int)es.x;
        if (r / npg != g) continue;
        int s = (int)es.y;
        float Y[9];
        sh_from_delta(pos[3 * r] - pos[3 * s], pos[3 * r + 1] - pos[3 * s + 1],
                      pos[3 * r + 2] - pos[3 * s + 2], Y);
#pragma unroll
        for (int jp = 0; jp < 9; ++jp) {
            float sv = SY[s * 16 + jp];
#pragma unroll
            for (int j = 0; j < 9; ++j) atomicAdd(&Ms[jp * 9 + j], sv * Y[j]);
        }
    }
    __syncthreads();
    if (tid < 10) {
        int c = tid;
        float z = 0.f;
#pragma unroll
        for (int idx = 0; idx < 81; ++idx) z += Gs[idx * 10 + c] * Ms[idx];
        float z2 = 0.f;
#pragma unroll
        for (int j = 0; j < 9; ++j) z2 += Hs[j * 10 + c] * Ms[81 + j];
        out[g * 10 + c] = w2[0] * (w1[0] * z + b1[0] * z2) + Cc[c];
    }
}

extern "C" void kernel_launch(void* const* d_in, const int* in_sizes, int n_in,
                              void* d_out, int out_size, void* d_ws, size_t ws_size,
                              hipStream_t stream) {
    const float* pos = (const float*)d_in[0];
    const float* w1  = (const float*)d_in[1];
    const float* b1  = (const float*)d_in[2];
    const float* w2  = (const float*)d_in[3];
    const float* b2  = (const float*)d_in[4];
    const float* wg  = (const float*)d_in[5];
    const float* bg  = (const float*)d_in[6];
    const int* snd   = (const int*)d_in[7];
    const int* rcv   = (const int*)d_in[8];

    int N = in_sizes[0] / 3;
    int E = in_sizes[7];
    int nG = out_size / 10;          // n_graphs
    int npg = N / nG;                // nodes per graph (800)

    float* ws = (float*)d_ws;
    float* A1  = ws + 0;       // 144
    float* K2  = ws + 144;     // 5184
    float* T2  = ws + 5328;    // 1440
    float* Cc  = ws + 6768;    // 16
    float* Gt  = ws + 6784;    // 816
    float* Ht  = ws + 7600;    // 96
    double* su2tab = (double*)(ws + 7696);        // 27720 doubles
    size_t c0 = 7696 + 2 * (size_t)SU2_TAB_SIZE;  // 63136
    size_t wsFloats = ws_size / 4;

    // ---- NEW layout (round-7 champion; phase4n is the only delta) ----
    // [count(16N, padded 1/line) | SY(16N) | olcnt(16) | bucket(BSLOT*N) |
    //  olist(2*OLCAP) | partial(nG*bpg4*90)]
    const int BSLOT = 40;
    int bpg4 = (npg + 255) / 256;                 // blocks per graph (800 -> 4)
    int nb   = (npg + bpg4 - 1) / bpg4;           // nodes per block (200)
    int NB4  = nG * bpg4;
    size_t sy_off    = c0 + 16 * (size_t)N;
    size_t olcnt_off = sy_off + 16 * (size_t)N;
    size_t zeroN     = 32 * (size_t)N + 16;
    size_t b0        = c0 + zeroN;
    size_t olist_off = b0 + (size_t)BSLOT * N;
    size_t part_off  = olist_off + 2 * (size_t)OLCAP;
    size_t new_end   = part_off + (size_t)NB4 * 90;
    bool newp = (npg * nG == N) && (nG > 0) && (nb <= 256) && (new_end <= wsFloats);

    if (newp) {
        int* count   = (int*)ws + c0;
        float* SY    = ws + sy_off;
        int* olcnt   = (int*)ws + olcnt_off;
        int* bucket  = (int*)ws + b0;
        uint2* olist = (uint2*)(ws + olist_off);
        float* part  = ws + part_off;
        phase1_k<<<SU2_BLOCKS + 128, 256, 0, stream>>>(su2tab, ws + c0, (long)zeroN);
        int nCH = (E + CH2D - 1) / CH2D;
        phase2d_k<<<TBL2_BLOCKS + nCH * 8, 256, 0, stream>>>(
            su2tab, A1, K2, rcv, snd, pos, count, bucket, olcnt, olist, SY, E, BSLOT);
        phase3_k<<<TBL3_BLOCKS + (2 * N + 255) / 256, 256, 0, stream>>>(
            K2, wg, b2, bg, npg, T2, Cc, pos, count, bucket, SY, N, BSLOT, 1, 16);
        phase4n_k<<<TBL4_BLOCKS + NB4, 256, 0, stream>>>(
            A1, T2, Gt, Ht, pos, count, bucket, SY, part, npg, BSLOT, bpg4, nb);
        final3_k<<<nG, 128, 0, stream>>>(Gt, Ht, part, Cc, w1, b1, w2, pos, SY,
                                         olcnt, olist, (float*)d_out, bpg4, npg);
    } else {
        // ---- OLD fallback: unpadded count | SY | olcnt | part | bucket ----
        int npb = 1;
        for (int d = 1; d <= 64 && d <= npg; ++d) if (npg % d == 0) npb = d;
        int K = 256 / npb; if (K > 8) K = 8;
        int bpg = (npb > 0) ? npg / npb : 1;
        int NB2 = nG * bpg;
        int* count = (int*)ws + c0;
        float* SY  = ws + c0 + N;
        int* olcnt = (int*)ws + c0 + 17 * (size_t)N;
        size_t zN  = 17 * (size_t)N + 16;
        size_t ob0 = c0 + zN;
        float* part = ws + ob0;
        size_t buck_off = ob0 + (size_t)NB2 * 90;
        int* bucket = (int*)ws + buck_off;
        long avail = (long)wsFloats - (long)buck_off;
        int slots = 0;
        if (avail > 0) slots = (int)(avail / (long)N);
        if (slots > 48) slots = 48;
        phase1_k<<<SU2_BLOCKS + 128, 256, 0, stream>>>(su2tab, ws + c0, (long)zN);
        phase2_k<<<TBL2_BLOCKS + (E + 255) / 256, 256, 0, stream>>>(
            su2tab, A1, K2, rcv, snd, pos, count, bucket, SY, E, N, slots);
        phase3_k<<<TBL3_BLOCKS + (2 * N + 255) / 256, 256, 0, stream>>>(
            K2, wg, b2, bg, npg, T2, Cc, pos, count, bucket, SY, N, slots, 0, 1);
        phase4_k<<<TBL4_BLOCKS + NB2, 256, 0, stream>>>(
            A1, T2, Gt, Ht, pos, snd, rcv, count, bucket, SY, part, N, E, slots, npb, K);
        final3_k<<<nG, 128, 0, stream>>>(Gt, Ht, part, Cc, w1, b1, w2, pos, SY,
                                         olcnt, (uint2*)(ws + olist_off), (float*)d_out,
                                         bpg, npg);
    }
}